// Round 1
// baseline (4804.254 us; speedup 1.0000x reference)
//
#include <hip/hip_runtime.h>

#define HID 256
#define N_FINE 262144
#define E_FINE 524288
#define N_COARSE 65536
#define E_COARSE 262144
#define NPITCH 260   // LDS row pitch for 256-wide activations (16B aligned, breaks 2^k strides)

static const size_t NODE_FLOATS = (size_t)N_COARSE * HID;   // 16,777,216
static const size_t EDGE_FLOATS = (size_t)E_COARSE * HID;   // 67,108,864
static const size_t IDX_OFF     = NODE_FLOATS + EDGE_FLOATS; // 83,886,080
#define IDX_N (2 * E_COARSE)                                 // 524,288

__device__ __forceinline__ float elu_f(float v) {
    return v > 0.0f ? v : (__expf(v) - 1.0f);
}

// ---------------- segment counts (int atomics) ----------------
__global__ __launch_bounds__(256) void counts_kernel(
    const int* __restrict__ f2ce, const int* __restrict__ f2ci,
    int* __restrict__ edgeCnt, int* __restrict__ nodeCnt)
{
    int i = blockIdx.x * 256 + threadIdx.x;   // grid covers E_FINE
    if (i < E_FINE) atomicAdd(&edgeCnt[f2ce[i]], 1);
    if (i < N_FINE) atomicAdd(&nodeCnt[f2ci[i]], 1);
}

// ---------------- edge feature scatter-sum ----------------
// one wave per fine edge: 64 lanes x float4 = the full 256-wide row
__global__ __launch_bounds__(256) void edge_scatter_kernel(
    const float* __restrict__ ea, const int* __restrict__ f2ce,
    float* __restrict__ edgeSum)
{
    int t = threadIdx.x;
    size_t e = (size_t)blockIdx.x * 4 + (t >> 6);
    int q = t & 63;
    const float4 v = *(const float4*)&ea[e * HID + q * 4];
    int c = f2ce[e];
    float* p = edgeSum + (size_t)c * HID + (size_t)q * 4;
    unsafeAtomicAdd(p + 0, v.x);
    unsafeAtomicAdd(p + 1, v.y);
    unsafeAtomicAdd(p + 2, v.z);
    unsafeAtomicAdd(p + 3, v.w);
}

// ---------------- fused MLP: one 256x256 layer, W streamed through LDS ----------------
__device__ __forceinline__ void gemm_layer(
    const float* __restrict__ Wg,   // [256][256] row-major, global
    const float* sIn,               // LDS [16][NPITCH]
    float* sW,                      // LDS [16][256]
    float acc[4][4], int t, int mb, int n0)
{
    for (int kt = 0; kt < 16; ++kt) {
        __syncthreads();   // protect sW from previous tile's readers
        const float* wsrc = Wg + (size_t)kt * 16 * HID;
        #pragma unroll
        for (int r = 0; r < 4; ++r) {
            int id = r * 256 + t;                 // 0..1023 -> 16KB tile
            *(float4*)&sW[id * 4] = *(const float4*)&wsrc[id * 4];
        }
        __syncthreads();
        #pragma unroll
        for (int k4 = 0; k4 < 4; ++k4) {
            int kb = kt * 16 + k4 * 4;
            float4 w[4];
            #pragma unroll
            for (int kk = 0; kk < 4; ++kk)
                w[kk] = *(const float4*)&sW[(k4 * 4 + kk) * HID + n0];
            #pragma unroll
            for (int i = 0; i < 4; ++i) {
                float4 av = *(const float4*)&sIn[(mb + i) * NPITCH + kb];
                float am[4] = {av.x, av.y, av.z, av.w};
                #pragma unroll
                for (int kk = 0; kk < 4; ++kk) {
                    acc[i][0] = fmaf(am[kk], w[kk].x, acc[i][0]);
                    acc[i][1] = fmaf(am[kk], w[kk].y, acc[i][1]);
                    acc[i][2] = fmaf(am[kk], w[kk].z, acc[i][2]);
                    acc[i][3] = fmaf(am[kk], w[kk].w, acc[i][3]);
                }
            }
        }
    }
}

__global__ __launch_bounds__(256) void mlp_kernel(
    const float* __restrict__ x, const float* __restrict__ dist,
    const int* __restrict__ f2ci,
    const float* __restrict__ W1, const float* __restrict__ b1,
    const float* __restrict__ W2, const float* __restrict__ b2,
    const float* __restrict__ W3, const float* __restrict__ b3,
    float* __restrict__ nodeSum)
{
    __shared__ float s0[16 * NPITCH];   // x tile, then h2
    __shared__ float s1[16 * NPITCH];   // h1
    __shared__ float sW[16 * HID];      // streamed W tile

    const int t  = threadIdx.x;
    const int m0 = blockIdx.x * 16;
    const int n0 = (t & 63) * 4;        // output-column quad
    const int mb = (t >> 6) * 4;        // node quad

    // stage x tile (coalesced: each wave copies full 1KB rows)
    #pragma unroll
    for (int r = 0; r < 4; ++r) {
        int id = r * 256 + t;
        int m = id >> 6, k4 = id & 63;
        *(float4*)&s0[m * NPITCH + k4 * 4] =
            *(const float4*)&x[(size_t)(m0 + m) * HID + (size_t)k4 * 4];
    }

    float acc[4][4];

    // ---- layer 1: elu([x,d] @ W1 + b1); distance column folded into init ----
    {
        float4 bv = *(const float4*)&b1[n0];
        float4 wl = *(const float4*)&W1[(size_t)HID * HID + n0];  // W1 row 256
        #pragma unroll
        for (int i = 0; i < 4; ++i) {
            float d = dist[m0 + mb + i];
            acc[i][0] = fmaf(d, wl.x, bv.x);
            acc[i][1] = fmaf(d, wl.y, bv.y);
            acc[i][2] = fmaf(d, wl.z, bv.z);
            acc[i][3] = fmaf(d, wl.w, bv.w);
        }
    }
    gemm_layer(W1, s0, sW, acc, t, mb, n0);
    #pragma unroll
    for (int i = 0; i < 4; ++i) {
        float4 v = make_float4(elu_f(acc[i][0]), elu_f(acc[i][1]),
                               elu_f(acc[i][2]), elu_f(acc[i][3]));
        *(float4*)&s1[(mb + i) * NPITCH + n0] = v;
    }

    // ---- layer 2: elu(h1 @ W2 + b2) -> s0 (x no longer needed in LDS) ----
    {
        float4 bv = *(const float4*)&b2[n0];
        #pragma unroll
        for (int i = 0; i < 4; ++i) {
            acc[i][0] = bv.x; acc[i][1] = bv.y; acc[i][2] = bv.z; acc[i][3] = bv.w;
        }
    }
    gemm_layer(W2, s1, sW, acc, t, mb, n0);
    #pragma unroll
    for (int i = 0; i < 4; ++i) {
        float4 v = make_float4(elu_f(acc[i][0]), elu_f(acc[i][1]),
                               elu_f(acc[i][2]), elu_f(acc[i][3]));
        *(float4*)&s0[(mb + i) * NPITCH + n0] = v;
    }

    // ---- layer 3: h2 @ W3 + b3, + residual x (re-read), scatter to coarse ----
    {
        float4 bv = *(const float4*)&b3[n0];
        #pragma unroll
        for (int i = 0; i < 4; ++i) {
            acc[i][0] = bv.x; acc[i][1] = bv.y; acc[i][2] = bv.z; acc[i][3] = bv.w;
        }
    }
    gemm_layer(W3, s0, sW, acc, t, mb, n0);
    #pragma unroll
    for (int i = 0; i < 4; ++i) {
        size_t m = (size_t)(m0 + mb + i);
        float4 xr = *(const float4*)&x[m * HID + n0];
        int c = f2ci[m];
        float* p = nodeSum + (size_t)c * HID + n0;
        unsafeAtomicAdd(p + 0, acc[i][0] + xr.x);
        unsafeAtomicAdd(p + 1, acc[i][1] + xr.y);
        unsafeAtomicAdd(p + 2, acc[i][2] + xr.z);
        unsafeAtomicAdd(p + 3, acc[i][3] + xr.w);
    }
}

// ---------------- divide sums by counts (both regions) ----------------
__global__ __launch_bounds__(256) void normalize_kernel(
    float* __restrict__ out, const int* __restrict__ edgeCnt,
    const int* __restrict__ nodeCnt)
{
    size_t i4 = (size_t)blockIdx.x * 256 + threadIdx.x;
    size_t f = i4 * 4;
    int cnt;
    if (f < NODE_FLOATS) cnt = nodeCnt[f >> 8];
    else                 cnt = edgeCnt[(f - NODE_FLOATS) >> 8];
    float s = 1.0f / (float)(cnt > 0 ? cnt : 1);
    float4 v = *(float4*)&out[f];
    v.x *= s; v.y *= s; v.z *= s; v.w *= s;
    *(float4*)&out[f] = v;
}

// ---------------- coarse_edge_index passthrough (as float) ----------------
__global__ __launch_bounds__(256) void idx_copy_kernel(
    const int* __restrict__ cei, float* __restrict__ out)
{
    int i = blockIdx.x * 256 + threadIdx.x;   // grid covers IDX_N
    out[IDX_OFF + i] = (float)cei[i];
}

extern "C" void kernel_launch(void* const* d_in, const int* in_sizes, int n_in,
                              void* d_out, int out_size, void* d_ws, size_t ws_size,
                              hipStream_t stream)
{
    const float* x    = (const float*)d_in[0];
    const float* ea   = (const float*)d_in[1];
    const float* dist = (const float*)d_in[2];
    const int*   f2ci = (const int*)d_in[3];
    const int*   f2ce = (const int*)d_in[4];
    const int*   cei  = (const int*)d_in[5];
    const float* W1   = (const float*)d_in[6];
    const float* b1   = (const float*)d_in[7];
    const float* W2   = (const float*)d_in[8];
    const float* b2   = (const float*)d_in[9];
    const float* W3   = (const float*)d_in[10];
    const float* b3   = (const float*)d_in[11];

    float* out     = (float*)d_out;
    float* nodeSum = out;                  // [65536][256]
    float* edgeSum = out + NODE_FLOATS;    // [262144][256]
    int*   edgeCnt = (int*)d_ws;           // 262144 ints
    int*   nodeCnt = edgeCnt + E_COARSE;   // 65536 ints

    hipMemsetAsync(d_out, 0, (NODE_FLOATS + EDGE_FLOATS) * sizeof(float), stream);
    hipMemsetAsync(d_ws, 0, (size_t)(E_COARSE + N_COARSE) * sizeof(int), stream);

    counts_kernel<<<E_FINE / 256, 256, 0, stream>>>(f2ce, f2ci, edgeCnt, nodeCnt);
    edge_scatter_kernel<<<E_FINE / 4, 256, 0, stream>>>(ea, f2ce, edgeSum);
    mlp_kernel<<<N_FINE / 16, 256, 0, stream>>>(x, dist, f2ci,
                                                W1, b1, W2, b2, W3, b3, nodeSum);
    normalize_kernel<<<(unsigned)((NODE_FLOATS + EDGE_FLOATS) / 4 / 256), 256, 0, stream>>>(
        out, edgeCnt, nodeCnt);
    idx_copy_kernel<<<IDX_N / 256, 256, 0, stream>>>(cei, out);
}